// Round 10
// baseline (273.502 us; speedup 1.0000x reference)
//
#include <hip/hip_runtime.h>

#define NN 100000
#define NF 128
#define NE 1600000
#define NBK 782   // ceil(NN/128) buckets of 128 dst nodes
#define CH 4096   // edges per binning chunk
#define MAXB 2816 // padded region per bucket (mean 2046, ~17 sigma headroom)
#define RED_B 512 // blocks for esum partial reduction
#define NGB 1563  // (NN+63)/64 gemm blocks
#define CVTXB 12500  // NN*NF/4/256 blocks for x-conversion

typedef unsigned short ushort_t;
typedef __attribute__((ext_vector_type(8))) short bf16x8;
typedef __attribute__((ext_vector_type(4))) float f32x4;

__device__ inline ushort_t f2bf(float f) {  // RNE
  union { float f; unsigned u; } v; v.f = f;
  const unsigned r = v.u + 0x7FFFu + ((v.u >> 16) & 1u);
  return (ushort_t)(r >> 16);
}
__device__ inline float bf2f(ushort_t h) {
  union { unsigned u; float f; } v; v.u = ((unsigned)h) << 16;
  return v.f;
}

// ---------------------------------------------- block-wide exclusive scan
__device__ inline void block_scan(const int* hist, int* lofs, int* wsum) {
  const int t = threadIdx.x;
  const int b4 = t * 4;
  const int h0 = hist[b4], h1 = hist[b4 + 1], h2 = hist[b4 + 2], h3 = hist[b4 + 3];
  const int tsum = h0 + h1 + h2 + h3;
  const int lane = t & 63, w = t >> 6;
  int s = tsum;
#pragma unroll
  for (int o = 1; o < 64; o <<= 1) {
    const int u = __shfl_up(s, o);
    if (lane >= o) s += u;
  }
  if (lane == 63) wsum[w] = s;
  __syncthreads();
  int add = 0;
  for (int i = 0; i < w; ++i) add += wsum[i];
  const int ex = add + s - tsum;
  lofs[b4] = ex;
  lofs[b4 + 1] = ex + h0;
  lofs[b4 + 2] = ex + h0 + h1;
  lofs[b4 + 3] = ex + h0 + h1 + h2;
}

// ------------------------------------------------ LDS-staged bucket binning
__global__ __launch_bounds__(256) void k_bin(const int* __restrict__ src,
                                             const int* __restrict__ dst,
                                             int* __restrict__ bcursor,
                                             int* __restrict__ packed) {
  __shared__ int hist[1024];
  __shared__ int lofs[1024];
  __shared__ int wsum[4];
  __shared__ int gofs[NBK];
  __shared__ int list[CH];
  __shared__ unsigned short blist[CH];
  const int t = threadIdx.x;
  const int e0 = blockIdx.x * CH;
  const int n = min(CH, NE - e0);

  for (int i = t; i < 1024; i += 256) hist[i] = 0;
  __syncthreads();
  for (int i = t; i < n; i += 256) atomicAdd(&hist[dst[e0 + i] >> 7], 1);
  __syncthreads();
  block_scan(hist, lofs, wsum);
  __syncthreads();
  for (int b = t; b < NBK; b += 256) {
    const int cnt = hist[b];
    gofs[b] = cnt ? atomicAdd(&bcursor[b], cnt) : 0;
    hist[b] = 0;
  }
  __syncthreads();
  for (int i = t; i < n; i += 256) {
    const int d = dst[e0 + i];
    const int s = src[e0 + i];
    const int b = d >> 7;
    const int r = atomicAdd(&hist[b], 1);
    const int q = lofs[b] + r;
    list[q] = ((d & 127) << 17) | s;
    blist[q] = (unsigned short)b;
  }
  __syncthreads();
  for (int q = t; q < n; q += 256) {
    const int b = blist[q];
    const int idx = gofs[b] + (q - lofs[b]);
    if (idx < MAXB) packed[b * MAXB + idx] = list[q];
  }
}

// --------------------------------- second-level sort: exact CSR per bucket
__global__ __launch_bounds__(256) void k_sort2(int* __restrict__ packed,
                                               const int* __restrict__ bcursor,
                                               int* __restrict__ offs,
                                               int* __restrict__ ends) {
  __shared__ int plist[MAXB];
  __shared__ int slist[MAXB];
  __shared__ int hist[128];
  __shared__ int lofs[128];
  __shared__ int wsum2[2];
  const int b = blockIdx.x, t = threadIdx.x;
  const int beg = b * MAXB;
  const int n = min(bcursor[b], MAXB);

  for (int i = t; i < n; i += 256) plist[i] = packed[beg + i];
  if (t < 128) hist[t] = 0;
  __syncthreads();
  for (int i = t; i < n; i += 256) atomicAdd(&hist[plist[i] >> 17], 1);
  __syncthreads();
  int s = (t < 128) ? hist[t] : 0;
  {
    const int lane = t & 63;
#pragma unroll
    for (int o = 1; o < 64; o <<= 1) {
      const int u = __shfl_up(s, o);
      if (lane >= o) s += u;
    }
    if (t < 128 && lane == 63) wsum2[t >> 6] = s;
  }
  __syncthreads();
  if (t < 128) {
    const int ex = s - hist[t] + ((t >= 64) ? wsum2[0] : 0);
    lofs[t] = ex;
    const int node = (b << 7) + t;
    if (node < NN) {
      offs[node] = beg + ex;
      ends[node] = beg + ex + hist[t];
    }
    hist[t] = 0;
  }
  __syncthreads();
  for (int i = t; i < n; i += 256) {
    const int p = plist[i];
    const int ld = p >> 17;
    const int r = atomicAdd(&hist[ld], 1);
    slist[lofs[ld] + r] = p & 0x1FFFF;
  }
  __syncthreads();
  for (int i = t; i < n; i += 256) packed[beg + i] = slist[i];
}

// -------------------------------- fp32 -> bf16 (features + all 4 weight mats)
__global__ __launch_bounds__(256) void k_cvt(const float* __restrict__ in,
                                             ushort_t* __restrict__ out,
                                             const float* __restrict__ w0,
                                             const float* __restrict__ w1,
                                             const float* __restrict__ w2,
                                             const float* __restrict__ w3,
                                             ushort_t* __restrict__ wout) {
  const int b = blockIdx.x;
  if (b < CVTXB) {
    const int i = b * 256 + threadIdx.x;
    const float4 v = *reinterpret_cast<const float4*>(in + i * 4);
    ushort4 o;
    o.x = f2bf(v.x); o.y = f2bf(v.y); o.z = f2bf(v.z); o.w = f2bf(v.w);
    *reinterpret_cast<ushort4*>(out + i * 4) = o;
  } else {
    const int i = (b - CVTXB) * 256 + threadIdx.x;  // 64 blocks x 256 = 16384
    wout[i] = f2bf(w0[i]);
    wout[16384 + i] = f2bf(w1[i]);
    wout[32768 + i] = f2bf(w2[i]);
    wout[49152 + i] = f2bf(w3[i]);
  }
}

// --------------------------------------------- gather-based aggregation (bf16)
// 2 nodes per wave: half-wave (32 lanes) per node, ushort4 (8B)/lane =
// 256B row per half. Unroll 16 -> 16 independent row-reads in flight per
// wave; 8 accumulator sets (pairs share) to bound VGPR.
__global__ __launch_bounds__(256) void k_agg(const ushort_t* __restrict__ feat,
                                             const int* __restrict__ offs,
                                             const int* __restrict__ ends,
                                             const int* __restrict__ srcs,
                                             ushort_t* __restrict__ out) {
  const int lane = threadIdx.x & 63;
  const int wid = threadIdx.x >> 6;
  const int node = blockIdx.x * 8 + wid * 2 + (lane >> 5);
  if (node >= NN) return;
  const int c = (lane & 31) * 4;
  const int beg = offs[node];
  const int end = ends[node];

  float ax[8], ay[8], az[8], aw[8];
#pragma unroll
  for (int k = 0; k < 8; ++k) { ax[k] = 0.f; ay[k] = 0.f; az[k] = 0.f; aw[k] = 0.f; }

  int e = beg;
  for (; e + 16 <= end; e += 16) {
    int s[16];
#pragma unroll
    for (int k = 0; k < 16; ++k) s[k] = srcs[e + k];
    ushort4 u[16];
#pragma unroll
    for (int k = 0; k < 16; ++k)
      u[k] = *(const ushort4*)(feat + s[k] * NF + c);
#pragma unroll
    for (int k = 0; k < 16; ++k) {
      const int kk = k & 7;
      ax[kk] += bf2f(u[k].x); ay[kk] += bf2f(u[k].y);
      az[kk] += bf2f(u[k].z); aw[kk] += bf2f(u[k].w);
    }
  }
  for (; e + 4 <= end; e += 4) {
    int s[4];
#pragma unroll
    for (int k = 0; k < 4; ++k) s[k] = srcs[e + k];
    ushort4 u[4];
#pragma unroll
    for (int k = 0; k < 4; ++k)
      u[k] = *(const ushort4*)(feat + s[k] * NF + c);
#pragma unroll
    for (int k = 0; k < 4; ++k) {
      ax[k] += bf2f(u[k].x); ay[k] += bf2f(u[k].y);
      az[k] += bf2f(u[k].z); aw[k] += bf2f(u[k].w);
    }
  }
  for (; e < end; ++e) {
    const ushort4 u = *(const ushort4*)(feat + srcs[e] * NF + c);
    ax[0] += bf2f(u.x); ay[0] += bf2f(u.y);
    az[0] += bf2f(u.z); aw[0] += bf2f(u.w);
  }

  ushort4 r;
  r.x = f2bf(((ax[0] + ax[1]) + (ax[2] + ax[3])) + ((ax[4] + ax[5]) + (ax[6] + ax[7])));
  r.y = f2bf(((ay[0] + ay[1]) + (ay[2] + ay[3])) + ((ay[4] + ay[5]) + (ay[6] + ay[7])));
  r.z = f2bf(((az[0] + az[1]) + (az[2] + az[3])) + ((az[4] + az[5]) + (az[6] + az[7])));
  r.w = f2bf(((aw[0] + aw[1]) + (aw[2] + aw[3])) + ((aw[4] + aw[5]) + (aw[6] + aw[7])));
  *(ushort4*)(out + node * NF + c) = r;
}

// ------------------------------------------------------------- MFMA GEMM
// MODE 0: write relu(v) as bf16 to out (layer 1).
// MODE 1: layer 2+3 fused epilogue via shfl_xor j-reduction:
//         y1[node] = h2.W3rel, P2[block] = sum_nodes h2.W3root.
template <int MODE>
__global__ __launch_bounds__(256) void k_gemm(const ushort_t* __restrict__ A1,
                                              const ushort_t* __restrict__ A2,
                                              const ushort_t* __restrict__ B1,
                                              const ushort_t* __restrict__ B2,
                                              const float* __restrict__ bias,
                                              ushort_t* __restrict__ out,
                                              const float* __restrict__ W3rel,
                                              const float* __restrict__ W3root,
                                              float* __restrict__ y1,
                                              float* __restrict__ P2) {
  __shared__ ushort_t As[64][264];  // +8 pad: 2-way LDS conflict only
  __shared__ float y1s[4][64];
  __shared__ float y2s[4][64];
  const int tid = threadIdx.x;
  const int lane = tid & 63;
  const int wid = tid >> 6;
  const int bm = blockIdx.x * 64;

  const int jb = wid * 32 + (lane & 15);
  const int kc = (lane >> 4) * 8;
  bf16x8 bfrag[2][8];
#pragma unroll
  for (int nt = 0; nt < 2; ++nt) {
    const int j = jb + nt * 16;
#pragma unroll
    for (int ks = 0; ks < 4; ++ks) {
      bfrag[nt][ks] = *reinterpret_cast<const bf16x8*>(B1 + j * 128 + ks * 32 + kc);
      bfrag[nt][ks + 4] = *reinterpret_cast<const bf16x8*>(B2 + j * 128 + ks * 32 + kc);
    }
  }

  {
    const int r = tid >> 2, p = tid & 3;
    const int node = bm + r;
#pragma unroll
    for (int s = 0; s < 2; ++s) {
      const ushort_t* __restrict__ sp = s ? A2 : A1;
#pragma unroll
      for (int q = 0; q < 4; ++q) {
        const int col = p * 32 + q * 8;
        bf16x8 v = (node < NN) ? *reinterpret_cast<const bf16x8*>(sp + node * 128 + col)
                               : (bf16x8)(short)0;
        *reinterpret_cast<bf16x8*>(&As[r][s * 128 + col]) = v;
      }
    }
  }
  __syncthreads();

  f32x4 acc[4][2];
#pragma unroll
  for (int mt = 0; mt < 4; ++mt) {
    acc[mt][0] = (f32x4)0.f;
    acc[mt][1] = (f32x4)0.f;
  }

  const int ar = lane & 15;
#pragma unroll
  for (int ks = 0; ks < 8; ++ks) {
#pragma unroll
    for (int mt = 0; mt < 4; ++mt) {
      const bf16x8 a = *reinterpret_cast<const bf16x8*>(&As[mt * 16 + ar][ks * 32 + kc]);
      acc[mt][0] = __builtin_amdgcn_mfma_f32_16x16x32_bf16(a, bfrag[0][ks], acc[mt][0], 0, 0, 0);
      acc[mt][1] = __builtin_amdgcn_mfma_f32_16x16x32_bf16(a, bfrag[1][ks], acc[mt][1], 0, 0, 0);
    }
  }

  // epilogue (C/D: col=lane&15 -> j, row=(lane>>4)*4+reg -> node)
  const int rg = (lane >> 4) * 4;
  if (MODE == 0) {
#pragma unroll
    for (int nt = 0; nt < 2; ++nt) {
      const int j = jb + nt * 16;
      const float bv = bias[j];
#pragma unroll
      for (int mt = 0; mt < 4; ++mt) {
#pragma unroll
        for (int r = 0; r < 4; ++r) {
          const int node = bm + mt * 16 + rg + r;
          if (node < NN) {
            const float v = fmaxf(acc[mt][nt][r] + bv, 0.f);
            out[node * 128 + j] = f2bf(v);
          }
        }
      }
    }
  } else {
    const float bv0 = bias[jb], bv1 = bias[jb + 16];
    const float wr0 = W3rel[jb], wr1 = W3rel[jb + 16];
    const float wt0 = W3root[jb], wt1 = W3root[jb + 16];
#pragma unroll
    for (int mt = 0; mt < 4; ++mt) {
#pragma unroll
      for (int r = 0; r < 4; ++r) {
        const float v0 = fmaxf(acc[mt][0][r] + bv0, 0.f);
        const float v1 = fmaxf(acc[mt][1][r] + bv1, 0.f);
        float s1 = v0 * wr0 + v1 * wr1;
        float s2 = v0 * wt0 + v1 * wt1;
#pragma unroll
        for (int o = 1; o < 16; o <<= 1) {
          s1 += __shfl_xor(s1, o);
          s2 += __shfl_xor(s2, o);
        }
        if ((lane & 15) == 0) {
          const int nloc = mt * 16 + rg + r;
          y1s[wid][nloc] = s1;
          y2s[wid][nloc] = s2;
        }
      }
    }
    __syncthreads();
    if (tid < 64) {
      const int node = bm + tid;
      const float s1 = (y1s[0][tid] + y1s[1][tid]) + (y1s[2][tid] + y1s[3][tid]);
      float p = (node < NN)
                    ? (y2s[0][tid] + y2s[1][tid]) + (y2s[2][tid] + y2s[3][tid])
                    : 0.f;
      if (node < NN) y1[node] = s1;
#pragma unroll
      for (int o = 32; o > 0; o >>= 1) p += __shfl_down(p, o);
      if (tid == 0) P2[blockIdx.x] = p;
    }
  }
}

// --------------------------- P1 partials: Σ_e y1[src_e] (L2-resident table)
__global__ __launch_bounds__(256) void k_esum(const int* __restrict__ src,
                                              const float* __restrict__ y1,
                                              float* __restrict__ P1) {
  float p = 0.f;
  const int stride = RED_B * 256;
  for (int e = blockIdx.x * 256 + threadIdx.x; e < NE; e += stride)
    p += y1[src[e]];
#pragma unroll
  for (int o = 32; o > 0; o >>= 1) p += __shfl_down(p, o);
  __shared__ float tmp[4];
  const int lane = threadIdx.x & 63, w = threadIdx.x >> 6;
  if (lane == 0) tmp[w] = p;
  __syncthreads();
  if (threadIdx.x == 0)
    P1[blockIdx.x] = (tmp[0] + tmp[1]) + (tmp[2] + tmp[3]);
}

__global__ __launch_bounds__(256) void k_final(const float* __restrict__ P1,
                                               const float* __restrict__ P2,
                                               const float* __restrict__ b3,
                                               float* __restrict__ out) {
  const int t = threadIdx.x;
  float v = P1[t] + P1[t + 256];
  for (int i = t; i < NGB; i += 256) v += P2[i];
#pragma unroll
  for (int o = 32; o > 0; o >>= 1) v += __shfl_down(v, o);
  __shared__ float tmp[4];
  if ((t & 63) == 0) tmp[t >> 6] = v;
  __syncthreads();
  if (t == 0)
    out[0] = ((tmp[0] + tmp[1]) + (tmp[2] + tmp[3])) * (1.0f / NN) + b3[0];
}

// ---------------------------------------------------------------------------
extern "C" void kernel_launch(void* const* d_in, const int* in_sizes, int n_in,
                              void* d_out, int out_size, void* d_ws, size_t ws_size,
                              hipStream_t stream) {
  const float* x = (const float*)d_in[0];
  const int* ei = (const int*)d_in[1];
  const float* W1rel = (const float*)d_in[2];
  const float* b1 = (const float*)d_in[3];
  const float* W1root = (const float*)d_in[4];
  const float* W2rel = (const float*)d_in[5];
  const float* b2 = (const float*)d_in[6];
  const float* W2root = (const float*)d_in[7];
  const float* W3rel = (const float*)d_in[8];
  const float* b3 = (const float*)d_in[9];
  const float* W3root = (const float*)d_in[10];

  const int* src = ei;       // edge_index[0]
  const int* dst = ei + NE;  // edge_index[1]

  char* ws = (char*)d_ws;
  size_t off = 0;
  ushort_t* xb   = (ushort_t*)(ws + off); off += (size_t)NN * NF * 2;  // 25.6 MB
  ushort_t* h1b  = (ushort_t*)(ws + off); off += (size_t)NN * NF * 2;  // 25.6 MB
  ushort_t* aggb = (ushort_t*)(ws + off); off += (size_t)NN * NF * 2;  // 25.6 MB
  ushort_t* Wb   = (ushort_t*)(ws + off); off += 65536 * 2;            // 128 KB
  int* offs    = (int*)(ws + off); off += (size_t)NN * 4;              // 400 KB
  int* ends    = (int*)(ws + off); off += (size_t)NN * 4;              // 400 KB
  float* y1    = (float*)(ws + off); off += (size_t)NN * 4;            // 400 KB
  int* bcursor = (int*)(ws + off); off += 1024 * 4;
  float* P1    = (float*)(ws + off); off += RED_B * 4;
  float* P2    = (float*)(ws + off); off += 2048 * 4;
  int* packed  = (int*)(ws + off); off += (size_t)NBK * MAXB * 4;      // 8.8 MB
  int* srcs    = packed;  // k_sort2 rewrites packed in place
  float* outp = (float*)d_out;

  hipMemsetAsync(bcursor, 0, 1024 * sizeof(int), stream);

  // CSR build + conversions
  k_bin<<<(NE + CH - 1) / CH, 256, 0, stream>>>(src, dst, bcursor, packed);
  k_sort2<<<NBK, 256, 0, stream>>>(packed, bcursor, offs, ends);
  k_cvt<<<CVTXB + 64, 256, 0, stream>>>(x, xb, W1rel, W1root, W2rel, W2root, Wb);

  // layer 1
  k_agg<<<(NN + 7) / 8, 256, 0, stream>>>(xb, offs, ends, srcs, aggb);
  k_gemm<0><<<NGB, 256, 0, stream>>>(aggb, xb, Wb, Wb + 16384, b1, h1b,
                                     nullptr, nullptr, nullptr, nullptr);

  // layer 2 + 3 epilogue fusion (h2 never stored)
  k_agg<<<(NN + 7) / 8, 256, 0, stream>>>(h1b, offs, ends, srcs, aggb);
  k_gemm<1><<<NGB, 256, 0, stream>>>(aggb, h1b, Wb + 32768, Wb + 49152, b2, nullptr,
                                     W3rel, W3root, y1, P2);

  // final: Σ_e y1[src_e] + Σ P2 -> scalar
  k_esum<<<RED_B, 256, 0, stream>>>(src, y1, P1);
  k_final<<<1, 256, 0, stream>>>(P1, P2, b3, outp);
}

// Round 11
// 256.367 us; speedup vs baseline: 1.0668x; 1.0668x over previous
//
#include <hip/hip_runtime.h>

#define NN 100000
#define NF 128
#define NE 1600000
#define NBK 782   // ceil(NN/128) buckets of 128 dst nodes
#define CH 2048   // edges per binning chunk (24KB LDS -> ~3 blocks/CU at 782 blocks)
#define MAXB 2816 // padded region per bucket (mean 2046, ~17 sigma headroom)
#define RED_B 512 // blocks for esum partial reduction
#define NGB 1563  // (NN+63)/64 gemm blocks
#define CVTXB 12500  // NN*NF/4/256 blocks for x-conversion

typedef unsigned short ushort_t;
typedef __attribute__((ext_vector_type(8))) short bf16x8;
typedef __attribute__((ext_vector_type(4))) float f32x4;

__device__ inline ushort_t f2bf(float f) {  // RNE
  union { float f; unsigned u; } v; v.f = f;
  const unsigned r = v.u + 0x7FFFu + ((v.u >> 16) & 1u);
  return (ushort_t)(r >> 16);
}
__device__ inline float bf2f(ushort_t h) {
  union { unsigned u; float f; } v; v.u = ((unsigned)h) << 16;
  return v.f;
}

// ---------------------------------------------- block-wide exclusive scan
__device__ inline void block_scan(const int* hist, int* lofs, int* wsum) {
  const int t = threadIdx.x;
  const int b4 = t * 4;
  const int h0 = hist[b4], h1 = hist[b4 + 1], h2 = hist[b4 + 2], h3 = hist[b4 + 3];
  const int tsum = h0 + h1 + h2 + h3;
  const int lane = t & 63, w = t >> 6;
  int s = tsum;
#pragma unroll
  for (int o = 1; o < 64; o <<= 1) {
    const int u = __shfl_up(s, o);
    if (lane >= o) s += u;
  }
  if (lane == 63) wsum[w] = s;
  __syncthreads();
  int add = 0;
  for (int i = 0; i < w; ++i) add += wsum[i];
  const int ex = add + s - tsum;
  lofs[b4] = ex;
  lofs[b4 + 1] = ex + h0;
  lofs[b4 + 2] = ex + h0 + h1;
  lofs[b4 + 3] = ex + h0 + h1 + h2;
}

// ------------------------------------------------ LDS-staged bucket binning
__global__ __launch_bounds__(256) void k_bin(const int* __restrict__ src,
                                             const int* __restrict__ dst,
                                             int* __restrict__ bcursor,
                                             int* __restrict__ packed) {
  __shared__ int hist[1024];
  __shared__ int lofs[1024];
  __shared__ int wsum[4];
  __shared__ int gofs[NBK];
  __shared__ int list[CH];
  __shared__ unsigned short blist[CH];
  const int t = threadIdx.x;
  const int e0 = blockIdx.x * CH;
  const int n = min(CH, NE - e0);

  for (int i = t; i < 1024; i += 256) hist[i] = 0;
  __syncthreads();
  for (int i = t; i < n; i += 256) atomicAdd(&hist[dst[e0 + i] >> 7], 1);
  __syncthreads();
  block_scan(hist, lofs, wsum);
  __syncthreads();
  for (int b = t; b < NBK; b += 256) {
    const int cnt = hist[b];
    gofs[b] = cnt ? atomicAdd(&bcursor[b], cnt) : 0;
    hist[b] = 0;
  }
  __syncthreads();
  for (int i = t; i < n; i += 256) {
    const int d = dst[e0 + i];
    const int s = src[e0 + i];
    const int b = d >> 7;
    const int r = atomicAdd(&hist[b], 1);
    const int q = lofs[b] + r;
    list[q] = ((d & 127) << 17) | s;
    blist[q] = (unsigned short)b;
  }
  __syncthreads();
  for (int q = t; q < n; q += 256) {
    const int b = blist[q];
    const int idx = gofs[b] + (q - lofs[b]);
    if (idx < MAXB) packed[b * MAXB + idx] = list[q];
  }
}

// --------------------------------- second-level sort: exact CSR per bucket
__global__ __launch_bounds__(256) void k_sort2(int* __restrict__ packed,
                                               const int* __restrict__ bcursor,
                                               int* __restrict__ offs,
                                               int* __restrict__ ends) {
  __shared__ int plist[MAXB];
  __shared__ int slist[MAXB];
  __shared__ int hist[128];
  __shared__ int lofs[128];
  __shared__ int wsum2[2];
  const int b = blockIdx.x, t = threadIdx.x;
  const int beg = b * MAXB;
  const int n = min(bcursor[b], MAXB);

  for (int i = t; i < n; i += 256) plist[i] = packed[beg + i];
  if (t < 128) hist[t] = 0;
  __syncthreads();
  for (int i = t; i < n; i += 256) atomicAdd(&hist[plist[i] >> 17], 1);
  __syncthreads();
  int s = (t < 128) ? hist[t] : 0;
  {
    const int lane = t & 63;
#pragma unroll
    for (int o = 1; o < 64; o <<= 1) {
      const int u = __shfl_up(s, o);
      if (lane >= o) s += u;
    }
    if (t < 128 && lane == 63) wsum2[t >> 6] = s;
  }
  __syncthreads();
  if (t < 128) {
    const int ex = s - hist[t] + ((t >= 64) ? wsum2[0] : 0);
    lofs[t] = ex;
    const int node = (b << 7) + t;
    if (node < NN) {
      offs[node] = beg + ex;
      ends[node] = beg + ex + hist[t];
    }
    hist[t] = 0;
  }
  __syncthreads();
  for (int i = t; i < n; i += 256) {
    const int p = plist[i];
    const int ld = p >> 17;
    const int r = atomicAdd(&hist[ld], 1);
    slist[lofs[ld] + r] = p & 0x1FFFF;
  }
  __syncthreads();
  for (int i = t; i < n; i += 256) packed[beg + i] = slist[i];
}

// ------------ fp32 -> bf16 (features + weights) + bcursor zero (one dispatch)
__global__ __launch_bounds__(256) void k_cvt(const float* __restrict__ in,
                                             ushort_t* __restrict__ out,
                                             const float* __restrict__ w0,
                                             const float* __restrict__ w1,
                                             const float* __restrict__ w2,
                                             const float* __restrict__ w3,
                                             ushort_t* __restrict__ wout,
                                             int* __restrict__ bcursor) {
  const int b = blockIdx.x;
  if (b < CVTXB) {
    const int i = b * 256 + threadIdx.x;
    const float4 v = *reinterpret_cast<const float4*>(in + i * 4);
    ushort4 o;
    o.x = f2bf(v.x); o.y = f2bf(v.y); o.z = f2bf(v.z); o.w = f2bf(v.w);
    *reinterpret_cast<ushort4*>(out + i * 4) = o;
  } else if (b < CVTXB + 64) {
    const int i = (b - CVTXB) * 256 + threadIdx.x;  // 64 blocks x 256 = 16384
    wout[i] = f2bf(w0[i]);
    wout[16384 + i] = f2bf(w1[i]);
    wout[32768 + i] = f2bf(w2[i]);
    wout[49152 + i] = f2bf(w3[i]);
  } else {
    const int i = threadIdx.x * 4;
    bcursor[i] = 0; bcursor[i + 1] = 0; bcursor[i + 2] = 0; bcursor[i + 3] = 0;
  }
}

// --------------------------------------------- gather-based aggregation (bf16)
// 2 nodes per wave: half-wave (32 lanes) per node, ushort4 (8B)/lane =
// 256B row per half. Unroll 8 -> 8 independent row-reads in flight per wave.
// (unroll 16 measured WORSE: VGPR/occupancy tradeoff, round 10)
__global__ __launch_bounds__(256) void k_agg(const ushort_t* __restrict__ feat,
                                             const int* __restrict__ offs,
                                             const int* __restrict__ ends,
                                             const int* __restrict__ srcs,
                                             ushort_t* __restrict__ out) {
  const int lane = threadIdx.x & 63;
  const int wid = threadIdx.x >> 6;
  const int node = blockIdx.x * 8 + wid * 2 + (lane >> 5);
  if (node >= NN) return;
  const int c = (lane & 31) * 4;
  const int beg = offs[node];
  const int end = ends[node];

  float x0 = 0.f, y0 = 0.f, z0 = 0.f, w0 = 0.f;
  float x1 = 0.f, y1 = 0.f, z1 = 0.f, w1 = 0.f;
  float x2 = 0.f, y2 = 0.f, z2 = 0.f, w2 = 0.f;
  float x3 = 0.f, y3 = 0.f, z3 = 0.f, w3 = 0.f;
  float x4 = 0.f, y4 = 0.f, z4 = 0.f, w4 = 0.f;
  float x5 = 0.f, y5 = 0.f, z5 = 0.f, w5 = 0.f;
  float x6 = 0.f, y6 = 0.f, z6 = 0.f, w6 = 0.f;
  float x7 = 0.f, y7 = 0.f, z7 = 0.f, w7 = 0.f;

  int e = beg;
  for (; e + 8 <= end; e += 8) {
    const int s0 = srcs[e], s1 = srcs[e + 1], s2 = srcs[e + 2], s3 = srcs[e + 3];
    const int s4 = srcs[e + 4], s5 = srcs[e + 5], s6 = srcs[e + 6], s7 = srcs[e + 7];
    const ushort4 u0 = *(const ushort4*)(feat + s0 * NF + c);
    const ushort4 u1 = *(const ushort4*)(feat + s1 * NF + c);
    const ushort4 u2 = *(const ushort4*)(feat + s2 * NF + c);
    const ushort4 u3 = *(const ushort4*)(feat + s3 * NF + c);
    const ushort4 u4 = *(const ushort4*)(feat + s4 * NF + c);
    const ushort4 u5 = *(const ushort4*)(feat + s5 * NF + c);
    const ushort4 u6 = *(const ushort4*)(feat + s6 * NF + c);
    const ushort4 u7 = *(const ushort4*)(feat + s7 * NF + c);
    x0 += bf2f(u0.x); y0 += bf2f(u0.y); z0 += bf2f(u0.z); w0 += bf2f(u0.w);
    x1 += bf2f(u1.x); y1 += bf2f(u1.y); z1 += bf2f(u1.z); w1 += bf2f(u1.w);
    x2 += bf2f(u2.x); y2 += bf2f(u2.y); z2 += bf2f(u2.z); w2 += bf2f(u2.w);
    x3 += bf2f(u3.x); y3 += bf2f(u3.y); z3 += bf2f(u3.z); w3 += bf2f(u3.w);
    x4 += bf2f(u4.x); y4 += bf2f(u4.y); z4 += bf2f(u4.z); w4 += bf2f(u4.w);
    x5 += bf2f(u5.x); y5 += bf2f(u5.y); z5 += bf2f(u5.z); w5 += bf2f(u5.w);
    x6 += bf2f(u6.x); y6 += bf2f(u6.y); z6 += bf2f(u6.z); w6 += bf2f(u6.w);
    x7 += bf2f(u7.x); y7 += bf2f(u7.y); z7 += bf2f(u7.z); w7 += bf2f(u7.w);
  }
  for (; e + 2 <= end; e += 2) {
    const int s0 = srcs[e], s1 = srcs[e + 1];
    const ushort4 u0 = *(const ushort4*)(feat + s0 * NF + c);
    const ushort4 u1 = *(const ushort4*)(feat + s1 * NF + c);
    x0 += bf2f(u0.x); y0 += bf2f(u0.y); z0 += bf2f(u0.z); w0 += bf2f(u0.w);
    x1 += bf2f(u1.x); y1 += bf2f(u1.y); z1 += bf2f(u1.z); w1 += bf2f(u1.w);
  }
  for (; e < end; ++e) {
    const int s = srcs[e];
    const ushort4 u = *(const ushort4*)(feat + s * NF + c);
    x0 += bf2f(u.x); y0 += bf2f(u.y); z0 += bf2f(u.z); w0 += bf2f(u.w);
  }
  ushort4 r;
  r.x = f2bf(((x0 + x1) + (x2 + x3)) + ((x4 + x5) + (x6 + x7)));
  r.y = f2bf(((y0 + y1) + (y2 + y3)) + ((y4 + y5) + (y6 + y7)));
  r.z = f2bf(((z0 + z1) + (z2 + z3)) + ((z4 + z5) + (z6 + z7)));
  r.w = f2bf(((w0 + w1) + (w2 + w3)) + ((w4 + w5) + (w6 + w7)));
  *(ushort4*)(out + node * NF + c) = r;
}

// ------------------------------------------------------------- MFMA GEMM
// MODE 0: write relu(v) as bf16 to out (layer 1).
// MODE 1: layer 2+3 fused epilogue via shfl_xor j-reduction:
//         y1[node] = h2.W3rel, P2[block] = sum_nodes h2.W3root.
template <int MODE>
__global__ __launch_bounds__(256) void k_gemm(const ushort_t* __restrict__ A1,
                                              const ushort_t* __restrict__ A2,
                                              const ushort_t* __restrict__ B1,
                                              const ushort_t* __restrict__ B2,
                                              const float* __restrict__ bias,
                                              ushort_t* __restrict__ out,
                                              const float* __restrict__ W3rel,
                                              const float* __restrict__ W3root,
                                              float* __restrict__ y1,
                                              float* __restrict__ P2) {
  __shared__ ushort_t As[64][264];  // +8 pad: 2-way LDS conflict only
  __shared__ float y1s[4][64];
  __shared__ float y2s[4][64];
  const int tid = threadIdx.x;
  const int lane = tid & 63;
  const int wid = tid >> 6;
  const int bm = blockIdx.x * 64;

  const int jb = wid * 32 + (lane & 15);
  const int kc = (lane >> 4) * 8;
  bf16x8 bfrag[2][8];
#pragma unroll
  for (int nt = 0; nt < 2; ++nt) {
    const int j = jb + nt * 16;
#pragma unroll
    for (int ks = 0; ks < 4; ++ks) {
      bfrag[nt][ks] = *reinterpret_cast<const bf16x8*>(B1 + j * 128 + ks * 32 + kc);
      bfrag[nt][ks + 4] = *reinterpret_cast<const bf16x8*>(B2 + j * 128 + ks * 32 + kc);
    }
  }

  {
    const int r = tid >> 2, p = tid & 3;
    const int node = bm + r;
#pragma unroll
    for (int s = 0; s < 2; ++s) {
      const ushort_t* __restrict__ sp = s ? A2 : A1;
#pragma unroll
      for (int q = 0; q < 4; ++q) {
        const int col = p * 32 + q * 8;
        bf16x8 v = (node < NN) ? *reinterpret_cast<const bf16x8*>(sp + node * 128 + col)
                               : (bf16x8)(short)0;
        *reinterpret_cast<bf16x8*>(&As[r][s * 128 + col]) = v;
      }
    }
  }
  __syncthreads();

  f32x4 acc[4][2];
#pragma unroll
  for (int mt = 0; mt < 4; ++mt) {
    acc[mt][0] = (f32x4)0.f;
    acc[mt][1] = (f32x4)0.f;
  }

  const int ar = lane & 15;
#pragma unroll
  for (int ks = 0; ks < 8; ++ks) {
#pragma unroll
    for (int mt = 0; mt < 4; ++mt) {
      const bf16x8 a = *reinterpret_cast<const bf16x8*>(&As[mt * 16 + ar][ks * 32 + kc]);
      acc[mt][0] = __builtin_amdgcn_mfma_f32_16x16x32_bf16(a, bfrag[0][ks], acc[mt][0], 0, 0, 0);
      acc[mt][1] = __builtin_amdgcn_mfma_f32_16x16x32_bf16(a, bfrag[1][ks], acc[mt][1], 0, 0, 0);
    }
  }

  // epilogue (C/D: col=lane&15 -> j, row=(lane>>4)*4+reg -> node)
  const int rg = (lane >> 4) * 4;
  if (MODE == 0) {
#pragma unroll
    for (int nt = 0; nt < 2; ++nt) {
      const int j = jb + nt * 16;
      const float bv = bias[j];
#pragma unroll
      for (int mt = 0; mt < 4; ++mt) {
#pragma unroll
        for (int r = 0; r < 4; ++r) {
          const int node = bm + mt * 16 + rg + r;
          if (node < NN) {
            const float v = fmaxf(acc[mt][nt][r] + bv, 0.f);
            out[node * 128 + j] = f2bf(v);
          }
        }
      }
    }
  } else {
    const float bv0 = bias[jb], bv1 = bias[jb + 16];
    const float wr0 = W3rel[jb], wr1 = W3rel[jb + 16];
    const float wt0 = W3root[jb], wt1 = W3root[jb + 16];
#pragma unroll
    for (int mt = 0; mt < 4; ++mt) {
#pragma unroll
      for (int r = 0; r < 4; ++r) {
        const float v0 = fmaxf(acc[mt][0][r] + bv0, 0.f);
        const float v1 = fmaxf(acc[mt][1][r] + bv1, 0.f);
        float s1 = v0 * wr0 + v1 * wr1;
        float s2 = v0 * wt0 + v1 * wt1;
#pragma unroll
        for (int o = 1; o < 16; o <<= 1) {
          s1 += __shfl_xor(s1, o);
          s2 += __shfl_xor(s2, o);
        }
        if ((lane & 15) == 0) {
          const int nloc = mt * 16 + rg + r;
          y1s[wid][nloc] = s1;
          y2s[wid][nloc] = s2;
        }
      }
    }
    __syncthreads();
    if (tid < 64) {
      const int node = bm + tid;
      const float s1 = (y1s[0][tid] + y1s[1][tid]) + (y1s[2][tid] + y1s[3][tid]);
      float p = (node < NN)
                    ? (y2s[0][tid] + y2s[1][tid]) + (y2s[2][tid] + y2s[3][tid])
                    : 0.f;
      if (node < NN) y1[node] = s1;
#pragma unroll
      for (int o = 32; o > 0; o >>= 1) p += __shfl_down(p, o);
      if (tid == 0) P2[blockIdx.x] = p;
    }
  }
}

// --------------------------- P1 partials: Σ_e y1[src_e] (L2-resident table)
__global__ __launch_bounds__(256) void k_esum(const int* __restrict__ src,
                                              const float* __restrict__ y1,
                                              float* __restrict__ P1) {
  float p = 0.f;
  const int stride = RED_B * 256;
  for (int e = blockIdx.x * 256 + threadIdx.x; e < NE; e += stride)
    p += y1[src[e]];
#pragma unroll
  for (int o = 32; o > 0; o >>= 1) p += __shfl_down(p, o);
  __shared__ float tmp[4];
  const int lane = threadIdx.x & 63, w = threadIdx.x >> 6;
  if (lane == 0) tmp[w] = p;
  __syncthreads();
  if (threadIdx.x == 0)
    P1[blockIdx.x] = (tmp[0] + tmp[1]) + (tmp[2] + tmp[3]);
}

__global__ __launch_bounds__(256) void k_final(const float* __restrict__ P1,
                                               const float* __restrict__ P2,
                                               const float* __restrict__ b3,
                                               float* __restrict__ out) {
  const int t = threadIdx.x;
  float v = P1[t] + P1[t + 256];
  for (int i = t; i < NGB; i += 256) v += P2[i];
#pragma unroll
  for (int o = 32; o > 0; o >>= 1) v += __shfl_down(v, o);
  __shared__ float tmp[4];
  if ((t & 63) == 0) tmp[t >> 6] = v;
  __syncthreads();
  if (t == 0)
    out[0] = ((tmp[0] + tmp[1]) + (tmp[2] + tmp[3])) * (1.0f / NN) + b3[0];
}

// ---------------------------------------------------------------------------
extern "C" void kernel_launch(void* const* d_in, const int* in_sizes, int n_in,
                              void* d_out, int out_size, void* d_ws, size_t ws_size,
                              hipStream_t stream) {
  const float* x = (const float*)d_in[0];
  const int* ei = (const int*)d_in[1];
  const float* W1rel = (const float*)d_in[2];
  const float* b1 = (const float*)d_in[3];
  const float* W1root = (const float*)d_in[4];
  const float* W2rel = (const float*)d_in[5];
  const float* b2 = (const float*)d_in[6];
  const float* W2root = (const float*)d_in[7];
  const float* W3rel = (const float*)d_in[8];
  const float* b3 = (const float*)d_in[9];
  const float* W3root = (const float*)d_in[10];

  const int* src = ei;       // edge_index[0]
  const int* dst = ei + NE;  // edge_index[1]

  char* ws = (char*)d_ws;
  size_t off = 0;
  ushort_t* xb   = (ushort_t*)(ws + off); off += (size_t)NN * NF * 2;  // 25.6 MB
  ushort_t* h1b  = (ushort_t*)(ws + off); off += (size_t)NN * NF * 2;  // 25.6 MB
  ushort_t* aggb = (ushort_t*)(ws + off); off += (size_t)NN * NF * 2;  // 25.6 MB
  ushort_t* Wb   = (ushort_t*)(ws + off); off += 65536 * 2;            // 128 KB
  int* offs    = (int*)(ws + off); off += (size_t)NN * 4;              // 400 KB
  int* ends    = (int*)(ws + off); off += (size_t)NN * 4;              // 400 KB
  float* y1    = (float*)(ws + off); off += (size_t)NN * 4;            // 400 KB
  int* bcursor = (int*)(ws + off); off += 1024 * 4;
  float* P1    = (float*)(ws + off); off += RED_B * 4;
  float* P2    = (float*)(ws + off); off += 2048 * 4;
  int* packed  = (int*)(ws + off); off += (size_t)NBK * MAXB * 4;      // 8.8 MB
  int* srcs    = packed;  // k_sort2 rewrites packed in place
  float* outp = (float*)d_out;

  // conversions + bcursor zero (must precede k_bin; one dispatch)
  k_cvt<<<CVTXB + 65, 256, 0, stream>>>(x, xb, W1rel, W1root, W2rel, W2root, Wb,
                                        bcursor);

  // CSR build
  k_bin<<<(NE + CH - 1) / CH, 256, 0, stream>>>(src, dst, bcursor, packed);
  k_sort2<<<NBK, 256, 0, stream>>>(packed, bcursor, offs, ends);

  // layer 1
  k_agg<<<(NN + 7) / 8, 256, 0, stream>>>(xb, offs, ends, srcs, aggb);
  k_gemm<0><<<NGB, 256, 0, stream>>>(aggb, xb, Wb, Wb + 16384, b1, h1b,
                                     nullptr, nullptr, nullptr, nullptr);

  // layer 2 + 3 epilogue fusion (h2 never stored)
  k_agg<<<(NN + 7) / 8, 256, 0, stream>>>(h1b, offs, ends, srcs, aggb);
  k_gemm<1><<<NGB, 256, 0, stream>>>(aggb, h1b, Wb + 32768, Wb + 49152, b2, nullptr,
                                     W3rel, W3root, y1, P2);

  // final: Σ_e y1[src_e] + Σ P2 -> scalar
  k_esum<<<RED_B, 256, 0, stream>>>(src, y1, P1);
  k_final<<<1, 256, 0, stream>>>(P1, P2, b3, outp);
}

// Round 12
// 244.517 us; speedup vs baseline: 1.1185x; 1.0485x over previous
//
#include <hip/hip_runtime.h>

#define NN 100000
#define NF 128
#define NE 1600000
#define NBK 782   // ceil(NN/128) buckets of 128 dst nodes
#define CH 4096   // edges per binning chunk (CH=2048 measured neutral-worse, r11)
#define BINB 391  // (NE+CH-1)/CH bin blocks
#define MAXB 2816 // padded region per bucket (mean 2046, ~17 sigma headroom)
#define RED_B 512 // blocks for esum partial reduction
#define NGB 1563  // (NN+63)/64 gemm blocks
#define CVTXB 12500  // NN*NF/4/256 blocks for x-conversion

typedef unsigned short ushort_t;
typedef __attribute__((ext_vector_type(8))) short bf16x8;
typedef __attribute__((ext_vector_type(4))) float f32x4;

__device__ inline ushort_t f2bf(float f) {  // RNE
  union { float f; unsigned u; } v; v.f = f;
  const unsigned r = v.u + 0x7FFFu + ((v.u >> 16) & 1u);
  return (ushort_t)(r >> 16);
}
__device__ inline float bf2f(ushort_t h) {
  union { unsigned u; float f; } v; v.u = ((unsigned)h) << 16;
  return v.f;
}

// ---------------------------------------------- block-wide exclusive scan
__device__ inline void block_scan(const int* hist, int* lofs, int* wsum) {
  const int t = threadIdx.x;
  const int b4 = t * 4;
  const int h0 = hist[b4], h1 = hist[b4 + 1], h2 = hist[b4 + 2], h3 = hist[b4 + 3];
  const int tsum = h0 + h1 + h2 + h3;
  const int lane = t & 63, w = t >> 6;
  int s = tsum;
#pragma unroll
  for (int o = 1; o < 64; o <<= 1) {
    const int u = __shfl_up(s, o);
    if (lane >= o) s += u;
  }
  if (lane == 63) wsum[w] = s;
  __syncthreads();
  int add = 0;
  for (int i = 0; i < w; ++i) add += wsum[i];
  const int ex = add + s - tsum;
  lofs[b4] = ex;
  lofs[b4 + 1] = ex + h0;
  lofs[b4 + 2] = ex + h0 + h1;
  lofs[b4 + 3] = ex + h0 + h1 + h2;
}

// ---------------- merged prep: bin (blocks 0..BINB) || weight cvt || x cvt
// Independent workloads co-scheduled in one dispatch: bin is LDS/atomic-bound,
// cvt is BW-bound -> they overlap instead of serializing on the stream.
__global__ __launch_bounds__(256) void k_prep(
    const int* __restrict__ src, const int* __restrict__ dst,
    int* __restrict__ bcursor, int* __restrict__ packed,
    const float* __restrict__ x, ushort_t* __restrict__ xb,
    const float* __restrict__ w0, const float* __restrict__ w1,
    const float* __restrict__ w2, const float* __restrict__ w3,
    ushort_t* __restrict__ wout) {
  __shared__ int hist[1024];
  __shared__ int lofs[1024];
  __shared__ int wsum[4];
  __shared__ int gofs[NBK];
  __shared__ int list[CH];
  __shared__ unsigned short blist[CH];
  const int blk = blockIdx.x;
  const int t = threadIdx.x;

  if (blk >= BINB + 64) {  // ---- x conversion (streaming)
    const int i = (blk - BINB - 64) * 256 + t;
    const float4 v = *reinterpret_cast<const float4*>(x + (size_t)i * 4);
    ushort4 o;
    o.x = f2bf(v.x); o.y = f2bf(v.y); o.z = f2bf(v.z); o.w = f2bf(v.w);
    *reinterpret_cast<ushort4*>(xb + (size_t)i * 4) = o;
    return;
  }
  if (blk >= BINB) {  // ---- weight conversion
    const int i = (blk - BINB) * 256 + t;
    wout[i] = f2bf(w0[i]);
    wout[16384 + i] = f2bf(w1[i]);
    wout[32768 + i] = f2bf(w2[i]);
    wout[49152 + i] = f2bf(w3[i]);
    return;
  }

  // ---- bin chunk
  const int e0 = blk * CH;
  const int n = min(CH, NE - e0);

  for (int i = t; i < 1024; i += 256) hist[i] = 0;
  __syncthreads();
  for (int i = t; i < n; i += 256) atomicAdd(&hist[dst[e0 + i] >> 7], 1);
  __syncthreads();
  block_scan(hist, lofs, wsum);
  __syncthreads();
  for (int b = t; b < NBK; b += 256) {
    const int cnt = hist[b];
    gofs[b] = cnt ? atomicAdd(&bcursor[b], cnt) : 0;
    hist[b] = 0;
  }
  __syncthreads();
  for (int i = t; i < n; i += 256) {
    const int d = dst[e0 + i];
    const int s = src[e0 + i];
    const int b = d >> 7;
    const int r = atomicAdd(&hist[b], 1);
    const int q = lofs[b] + r;
    list[q] = ((d & 127) << 17) | s;
    blist[q] = (unsigned short)b;
  }
  __syncthreads();
  for (int q = t; q < n; q += 256) {
    const int b = blist[q];
    const int idx = gofs[b] + (q - lofs[b]);
    if (idx < MAXB) packed[b * MAXB + idx] = list[q];
  }
}

// --------------------------------- second-level sort: exact CSR per bucket
__global__ __launch_bounds__(256) void k_sort2(int* __restrict__ packed,
                                               const int* __restrict__ bcursor,
                                               int* __restrict__ offs,
                                               int* __restrict__ ends) {
  __shared__ int plist[MAXB];
  __shared__ int slist[MAXB];
  __shared__ int hist[128];
  __shared__ int lofs[128];
  __shared__ int wsum2[2];
  const int b = blockIdx.x, t = threadIdx.x;
  const int beg = b * MAXB;
  const int n = min(bcursor[b], MAXB);

  for (int i = t; i < n; i += 256) plist[i] = packed[beg + i];
  if (t < 128) hist[t] = 0;
  __syncthreads();
  for (int i = t; i < n; i += 256) atomicAdd(&hist[plist[i] >> 17], 1);
  __syncthreads();
  int s = (t < 128) ? hist[t] : 0;
  {
    const int lane = t & 63;
#pragma unroll
    for (int o = 1; o < 64; o <<= 1) {
      const int u = __shfl_up(s, o);
      if (lane >= o) s += u;
    }
    if (t < 128 && lane == 63) wsum2[t >> 6] = s;
  }
  __syncthreads();
  if (t < 128) {
    const int ex = s - hist[t] + ((t >= 64) ? wsum2[0] : 0);
    lofs[t] = ex;
    const int node = (b << 7) + t;
    if (node < NN) {
      offs[node] = beg + ex;
      ends[node] = beg + ex + hist[t];
    }
    hist[t] = 0;
  }
  __syncthreads();
  for (int i = t; i < n; i += 256) {
    const int p = plist[i];
    const int ld = p >> 17;
    const int r = atomicAdd(&hist[ld], 1);
    slist[lofs[ld] + r] = p & 0x1FFFF;
  }
  __syncthreads();
  for (int i = t; i < n; i += 256) packed[beg + i] = slist[i];
}

// --------------------------------------------- gather-based aggregation (bf16)
// 2 nodes per wave: half-wave (32 lanes) per node, ushort4 (8B)/lane =
// 256B row per half. Unroll 8 (unroll 16 measured WORSE: VGPR/occ, r10).
__global__ __launch_bounds__(256) void k_agg(const ushort_t* __restrict__ feat,
                                             const int* __restrict__ offs,
                                             const int* __restrict__ ends,
                                             const int* __restrict__ srcs,
                                             ushort_t* __restrict__ out) {
  const int lane = threadIdx.x & 63;
  const int wid = threadIdx.x >> 6;
  const int node = blockIdx.x * 8 + wid * 2 + (lane >> 5);
  if (node >= NN) return;
  const int c = (lane & 31) * 4;
  const int beg = offs[node];
  const int end = ends[node];

  float x0 = 0.f, y0 = 0.f, z0 = 0.f, w0 = 0.f;
  float x1 = 0.f, y1 = 0.f, z1 = 0.f, w1 = 0.f;
  float x2 = 0.f, y2 = 0.f, z2 = 0.f, w2 = 0.f;
  float x3 = 0.f, y3 = 0.f, z3 = 0.f, w3 = 0.f;
  float x4 = 0.f, y4 = 0.f, z4 = 0.f, w4 = 0.f;
  float x5 = 0.f, y5 = 0.f, z5 = 0.f, w5 = 0.f;
  float x6 = 0.f, y6 = 0.f, z6 = 0.f, w6 = 0.f;
  float x7 = 0.f, y7 = 0.f, z7 = 0.f, w7 = 0.f;

  int e = beg;
  for (; e + 8 <= end; e += 8) {
    const int s0 = srcs[e], s1 = srcs[e + 1], s2 = srcs[e + 2], s3 = srcs[e + 3];
    const int s4 = srcs[e + 4], s5 = srcs[e + 5], s6 = srcs[e + 6], s7 = srcs[e + 7];
    const ushort4 u0 = *(const ushort4*)(feat + s0 * NF + c);
    const ushort4 u1 = *(const ushort4*)(feat + s1 * NF + c);
    const ushort4 u2 = *(const ushort4*)(feat + s2 * NF + c);
    const ushort4 u3 = *(const ushort4*)(feat + s3 * NF + c);
    const ushort4 u4 = *(const ushort4*)(feat + s4 * NF + c);
    const ushort4 u5 = *(const ushort4*)(feat + s5 * NF + c);
    const ushort4 u6 = *(const ushort4*)(feat + s6 * NF + c);
    const ushort4 u7 = *(const ushort4*)(feat + s7 * NF + c);
    x0 += bf2f(u0.x); y0 += bf2f(u0.y); z0 += bf2f(u0.z); w0 += bf2f(u0.w);
    x1 += bf2f(u1.x); y1 += bf2f(u1.y); z1 += bf2f(u1.z); w1 += bf2f(u1.w);
    x2 += bf2f(u2.x); y2 += bf2f(u2.y); z2 += bf2f(u2.z); w2 += bf2f(u2.w);
    x3 += bf2f(u3.x); y3 += bf2f(u3.y); z3 += bf2f(u3.z); w3 += bf2f(u3.w);
    x4 += bf2f(u4.x); y4 += bf2f(u4.y); z4 += bf2f(u4.z); w4 += bf2f(u4.w);
    x5 += bf2f(u5.x); y5 += bf2f(u5.y); z5 += bf2f(u5.z); w5 += bf2f(u5.w);
    x6 += bf2f(u6.x); y6 += bf2f(u6.y); z6 += bf2f(u6.z); w6 += bf2f(u6.w);
    x7 += bf2f(u7.x); y7 += bf2f(u7.y); z7 += bf2f(u7.z); w7 += bf2f(u7.w);
  }
  for (; e + 2 <= end; e += 2) {
    const int s0 = srcs[e], s1 = srcs[e + 1];
    const ushort4 u0 = *(const ushort4*)(feat + s0 * NF + c);
    const ushort4 u1 = *(const ushort4*)(feat + s1 * NF + c);
    x0 += bf2f(u0.x); y0 += bf2f(u0.y); z0 += bf2f(u0.z); w0 += bf2f(u0.w);
    x1 += bf2f(u1.x); y1 += bf2f(u1.y); z1 += bf2f(u1.z); w1 += bf2f(u1.w);
  }
  for (; e < end; ++e) {
    const int s = srcs[e];
    const ushort4 u = *(const ushort4*)(feat + s * NF + c);
    x0 += bf2f(u.x); y0 += bf2f(u.y); z0 += bf2f(u.z); w0 += bf2f(u.w);
  }
  ushort4 r;
  r.x = f2bf(((x0 + x1) + (x2 + x3)) + ((x4 + x5) + (x6 + x7)));
  r.y = f2bf(((y0 + y1) + (y2 + y3)) + ((y4 + y5) + (y6 + y7)));
  r.z = f2bf(((z0 + z1) + (z2 + z3)) + ((z4 + z5) + (z6 + z7)));
  r.w = f2bf(((w0 + w1) + (w2 + w3)) + ((w4 + w5) + (w6 + w7)));
  *(ushort4*)(out + node * NF + c) = r;
}

// ------------------------------------------------------------- MFMA GEMM
// MODE 0: write relu(v) as bf16 to out (layer 1).
// MODE 1: layer 2+3 fused epilogue via shfl_xor j-reduction:
//         y1[node] = h2.W3rel, P2[block] = sum_nodes h2.W3root.
template <int MODE>
__global__ __launch_bounds__(256) void k_gemm(const ushort_t* __restrict__ A1,
                                              const ushort_t* __restrict__ A2,
                                              const ushort_t* __restrict__ B1,
                                              const ushort_t* __restrict__ B2,
                                              const float* __restrict__ bias,
                                              ushort_t* __restrict__ out,
                                              const float* __restrict__ W3rel,
                                              const float* __restrict__ W3root,
                                              float* __restrict__ y1,
                                              float* __restrict__ P2) {
  __shared__ ushort_t As[64][264];  // +8 pad: 2-way LDS conflict only
  __shared__ float y1s[4][64];
  __shared__ float y2s[4][64];
  const int tid = threadIdx.x;
  const int lane = tid & 63;
  const int wid = tid >> 6;
  const int bm = blockIdx.x * 64;

  const int jb = wid * 32 + (lane & 15);
  const int kc = (lane >> 4) * 8;
  bf16x8 bfrag[2][8];
#pragma unroll
  for (int nt = 0; nt < 2; ++nt) {
    const int j = jb + nt * 16;
#pragma unroll
    for (int ks = 0; ks < 4; ++ks) {
      bfrag[nt][ks] = *reinterpret_cast<const bf16x8*>(B1 + j * 128 + ks * 32 + kc);
      bfrag[nt][ks + 4] = *reinterpret_cast<const bf16x8*>(B2 + j * 128 + ks * 32 + kc);
    }
  }

  {
    const int r = tid >> 2, p = tid & 3;
    const int node = bm + r;
#pragma unroll
    for (int s = 0; s < 2; ++s) {
      const ushort_t* __restrict__ sp = s ? A2 : A1;
#pragma unroll
      for (int q = 0; q < 4; ++q) {
        const int col = p * 32 + q * 8;
        bf16x8 v = (node < NN) ? *reinterpret_cast<const bf16x8*>(sp + node * 128 + col)
                               : (bf16x8)(short)0;
        *reinterpret_cast<bf16x8*>(&As[r][s * 128 + col]) = v;
      }
    }
  }
  __syncthreads();

  f32x4 acc[4][2];
#pragma unroll
  for (int mt = 0; mt < 4; ++mt) {
    acc[mt][0] = (f32x4)0.f;
    acc[mt][1] = (f32x4)0.f;
  }

  const int ar = lane & 15;
#pragma unroll
  for (int ks = 0; ks < 8; ++ks) {
#pragma unroll
    for (int mt = 0; mt < 4; ++mt) {
      const bf16x8 a = *reinterpret_cast<const bf16x8*>(&As[mt * 16 + ar][ks * 32 + kc]);
      acc[mt][0] = __builtin_amdgcn_mfma_f32_16x16x32_bf16(a, bfrag[0][ks], acc[mt][0], 0, 0, 0);
      acc[mt][1] = __builtin_amdgcn_mfma_f32_16x16x32_bf16(a, bfrag[1][ks], acc[mt][1], 0, 0, 0);
    }
  }

  // epilogue (C/D: col=lane&15 -> j, row=(lane>>4)*4+reg -> node)
  const int rg = (lane >> 4) * 4;
  if (MODE == 0) {
#pragma unroll
    for (int nt = 0; nt < 2; ++nt) {
      const int j = jb + nt * 16;
      const float bv = bias[j];
#pragma unroll
      for (int mt = 0; mt < 4; ++mt) {
#pragma unroll
        for (int r = 0; r < 4; ++r) {
          const int node = bm + mt * 16 + rg + r;
          if (node < NN) {
            const float v = fmaxf(acc[mt][nt][r] + bv, 0.f);
            out[node * 128 + j] = f2bf(v);
          }
        }
      }
    }
  } else {
    const float bv0 = bias[jb], bv1 = bias[jb + 16];
    const float wr0 = W3rel[jb], wr1 = W3rel[jb + 16];
    const float wt0 = W3root[jb], wt1 = W3root[jb + 16];
#pragma unroll
    for (int mt = 0; mt < 4; ++mt) {
#pragma unroll
      for (int r = 0; r < 4; ++r) {
        const float v0 = fmaxf(acc[mt][0][r] + bv0, 0.f);
        const float v1 = fmaxf(acc[mt][1][r] + bv1, 0.f);
        float s1 = v0 * wr0 + v1 * wr1;
        float s2 = v0 * wt0 + v1 * wt1;
#pragma unroll
        for (int o = 1; o < 16; o <<= 1) {
          s1 += __shfl_xor(s1, o);
          s2 += __shfl_xor(s2, o);
        }
        if ((lane & 15) == 0) {
          const int nloc = mt * 16 + rg + r;
          y1s[wid][nloc] = s1;
          y2s[wid][nloc] = s2;
        }
      }
    }
    __syncthreads();
    if (tid < 64) {
      const int node = bm + tid;
      const float s1 = (y1s[0][tid] + y1s[1][tid]) + (y1s[2][tid] + y1s[3][tid]);
      float p = (node < NN)
                    ? (y2s[0][tid] + y2s[1][tid]) + (y2s[2][tid] + y2s[3][tid])
                    : 0.f;
      if (node < NN) y1[node] = s1;
#pragma unroll
      for (int o = 32; o > 0; o >>= 1) p += __shfl_down(p, o);
      if (tid == 0) P2[blockIdx.x] = p;
    }
  }
}

// --------------------------- P1 partials: Σ_e y1[src_e] (L2-resident table)
__global__ __launch_bounds__(256) void k_esum(const int* __restrict__ src,
                                              const float* __restrict__ y1,
                                              float* __restrict__ P1) {
  float p = 0.f;
  const int stride = RED_B * 256;
  for (int e = blockIdx.x * 256 + threadIdx.x; e < NE; e += stride)
    p += y1[src[e]];
#pragma unroll
  for (int o = 32; o > 0; o >>= 1) p += __shfl_down(p, o);
  __shared__ float tmp[4];
  const int lane = threadIdx.x & 63, w = threadIdx.x >> 6;
  if (lane == 0) tmp[w] = p;
  __syncthreads();
  if (threadIdx.x == 0)
    P1[blockIdx.x] = (tmp[0] + tmp[1]) + (tmp[2] + tmp[3]);
}

__global__ __launch_bounds__(256) void k_final(const float* __restrict__ P1,
                                               const float* __restrict__ P2,
                                               const float* __restrict__ b3,
                                               float* __restrict__ out) {
  const int t = threadIdx.x;
  float v = P1[t] + P1[t + 256];
  for (int i = t; i < NGB; i += 256) v += P2[i];
#pragma unroll
  for (int o = 32; o > 0; o >>= 1) v += __shfl_down(v, o);
  __shared__ float tmp[4];
  if ((t & 63) == 0) tmp[t >> 6] = v;
  __syncthreads();
  if (t == 0)
    out[0] = ((tmp[0] + tmp[1]) + (tmp[2] + tmp[3])) * (1.0f / NN) + b3[0];
}

// ---------------------------------------------------------------------------
extern "C" void kernel_launch(void* const* d_in, const int* in_sizes, int n_in,
                              void* d_out, int out_size, void* d_ws, size_t ws_size,
                              hipStream_t stream) {
  const float* x = (const float*)d_in[0];
  const int* ei = (const int*)d_in[1];
  const float* W1rel = (const float*)d_in[2];
  const float* b1 = (const float*)d_in[3];
  const float* W1root = (const float*)d_in[4];
  const float* W2rel = (const float*)d_in[5];
  const float* b2 = (const float*)d_in[6];
  const float* W2root = (const float*)d_in[7];
  const float* W3rel = (const float*)d_in[8];
  const float* b3 = (const float*)d_in[9];
  const float* W3root = (const float*)d_in[10];

  const int* src = ei;       // edge_index[0]
  const int* dst = ei + NE;  // edge_index[1]

  char* ws = (char*)d_ws;
  size_t off = 0;
  ushort_t* xb   = (ushort_t*)(ws + off); off += (size_t)NN * NF * 2;  // 25.6 MB
  ushort_t* h1b  = (ushort_t*)(ws + off); off += (size_t)NN * NF * 2;  // 25.6 MB
  ushort_t* aggb = (ushort_t*)(ws + off); off += (size_t)NN * NF * 2;  // 25.6 MB
  ushort_t* Wb   = (ushort_t*)(ws + off); off += 65536 * 2;            // 128 KB
  int* offs    = (int*)(ws + off); off += (size_t)NN * 4;              // 400 KB
  int* ends    = (int*)(ws + off); off += (size_t)NN * 4;              // 400 KB
  float* y1    = (float*)(ws + off); off += (size_t)NN * 4;            // 400 KB
  int* bcursor = (int*)(ws + off); off += 1024 * 4;
  float* P1    = (float*)(ws + off); off += RED_B * 4;
  float* P2    = (float*)(ws + off); off += 2048 * 4;
  int* packed  = (int*)(ws + off); off += (size_t)NBK * MAXB * 4;      // 8.8 MB
  int* srcs    = packed;  // k_sort2 rewrites packed in place
  float* outp = (float*)d_out;

  hipMemsetAsync(bcursor, 0, 1024 * sizeof(int), stream);

  // merged prep: bin || weight-cvt || x-cvt (concurrent in one dispatch)
  k_prep<<<BINB + 64 + CVTXB, 256, 0, stream>>>(src, dst, bcursor, packed,
                                                x, xb, W1rel, W1root, W2rel,
                                                W2root, Wb);
  k_sort2<<<NBK, 256, 0, stream>>>(packed, bcursor, offs, ends);

  // layer 1
  k_agg<<<(NN + 7) / 8, 256, 0, stream>>>(xb, offs, ends, srcs, aggb);
  k_gemm<0><<<NGB, 256, 0, stream>>>(aggb, xb, Wb, Wb + 16384, b1, h1b,
                                     nullptr, nullptr, nullptr, nullptr);

  // layer 2 + 3 epilogue fusion (h2 never stored)
  k_agg<<<(NN + 7) / 8, 256, 0, stream>>>(h1b, offs, ends, srcs, aggb);
  k_gemm<1><<<NGB, 256, 0, stream>>>(aggb, h1b, Wb + 32768, Wb + 49152, b2, nullptr,
                                     W3rel, W3root, y1, P2);

  // final: Σ_e y1[src_e] + Σ P2 -> scalar
  k_esum<<<RED_B, 256, 0, stream>>>(src, y1, P1);
  k_final<<<1, 256, 0, stream>>>(P1, P2, b3, outp);
}